// Round 3
// baseline (542.490 us; speedup 1.0000x reference)
//
#include <hip/hip_runtime.h>

// ---------------------------------------------------------------------------
// Fused causal attention, MI355X gfx950.
// cast fp32->f16 -> QKV GEMM -> V transpose -> flash attention (operand-swap,
// gld16-staged K/V, 64 q/wave) -> output GEMM (fp32 out).
// MFMA 16x16x32 layouts (m89/m91/m120-verified):
//   A-frag: A[m=lane&15][k=(lane>>4)*8+j], j=0..7
//   B-frag: B[k=(lane>>4)*8+j][n=lane&15]
//   C/D   : row=(lane>>4)*4+reg, col=lane&15
// Attention uses the swap: St = K*Q^T (C: row=key,col=q), O^T = V^T*P.
// ---------------------------------------------------------------------------

typedef _Float16 f16x8 __attribute__((ext_vector_type(8)));
typedef float floatx4 __attribute__((ext_vector_type(4)));

union U4H8 { uint4 u; f16x8 h; };

__device__ __forceinline__ ushort f32_to_h_bits(float f) {
  _Float16 h = (_Float16)f;
  return __builtin_bit_cast(ushort, h);
}
__device__ __forceinline__ uint pack2h(float a, float b) {
  return (uint)f32_to_h_bits(a) | ((uint)f32_to_h_bits(b) << 16);
}

// async global->LDS, 16B/lane; LDS dest = wave-uniform base + lane*16
__device__ __forceinline__ void gld16(const void* g, void* l) {
  __builtin_amdgcn_global_load_lds(
      (const __attribute__((address_space(1))) unsigned char*)g,
      (__attribute__((address_space(3))) unsigned char*)l, 16, 0, 0);
}

// ---------------------------------------------------------------- cast kernel
__global__ __launch_bounds__(256) void cast_f32_f16(const float* __restrict__ in,
                                                    ushort* __restrict__ out) {
  int i = blockIdx.x * 256 + threadIdx.x;
  float4 v = ((const float4*)in)[i];
  ushort4 o;
  o.x = f32_to_h_bits(v.x);
  o.y = f32_to_h_bits(v.y);
  o.z = f32_to_h_bits(v.z);
  o.w = f32_to_h_bits(v.w);
  ((ushort4*)out)[i] = o;
}

// ------------------------------------------------------------------ GEMM B^T
// C[M,N] = A[M,K] * B[N,K]^T.  128x128 tile, BK=32, 4 waves 2x2, 4x4 MFMA.
template <int OUT_F16>
__global__ __launch_bounds__(256) void gemm_bt(const ushort* __restrict__ A,
                                               const ushort* __restrict__ B,
                                               void* __restrict__ Cv,
                                               int M, int N, int K) {
  __shared__ ushort As[128 * 32];
  __shared__ ushort Bs[128 * 32];

  const int tid = threadIdx.x;
  const int lane = tid & 63;
  const int wid = tid >> 6;
  const int l15 = lane & 15;
  const int quad = lane >> 4;
  const int m0 = blockIdx.y * 128;
  const int n0 = blockIdx.x * 128;
  const int wm = (wid & 1) * 64;
  const int wn = (wid >> 1) * 64;

  floatx4 acc[4][4];
#pragma unroll
  for (int i = 0; i < 4; i++)
#pragma unroll
    for (int j = 0; j < 4; j++) acc[i][j] = (floatx4){0.f, 0.f, 0.f, 0.f};

  const int srow = tid >> 2;
  const int scol = (tid & 3) * 8;
  const ushort* Ap0 = A + (size_t)(m0 + srow) * K + scol;
  const ushort* Ap1 = A + (size_t)(m0 + 64 + srow) * K + scol;
  const ushort* Bp0 = B + (size_t)(n0 + srow) * K + scol;
  const ushort* Bp1 = B + (size_t)(n0 + 64 + srow) * K + scol;
  ushort* AsW = As + wid * 512;
  ushort* BsW = Bs + wid * 512;

  for (int k0 = 0; k0 < K; k0 += 32) {
    __syncthreads();
    gld16(Ap0 + k0, AsW);
    gld16(Ap1 + k0, AsW + 2048);
    gld16(Bp0 + k0, BsW);
    gld16(Bp1 + k0, BsW + 2048);
    __syncthreads();

    U4H8 af[4], bf[4];
#pragma unroll
    for (int mi = 0; mi < 4; mi++)
      af[mi].u = *(const uint4*)&As[(wm + mi * 16 + l15) * 32 + quad * 8];
#pragma unroll
    for (int ni = 0; ni < 4; ni++)
      bf[ni].u = *(const uint4*)&Bs[(wn + ni * 16 + l15) * 32 + quad * 8];
#pragma unroll
    for (int mi = 0; mi < 4; mi++)
#pragma unroll
      for (int ni = 0; ni < 4; ni++)
        acc[mi][ni] = __builtin_amdgcn_mfma_f32_16x16x32_f16(af[mi].h, bf[ni].h,
                                                             acc[mi][ni], 0, 0, 0);
  }

#pragma unroll
  for (int mi = 0; mi < 4; mi++) {
#pragma unroll
    for (int r = 0; r < 4; r++) {
      size_t row = m0 + wm + mi * 16 + quad * 4 + r;
#pragma unroll
      for (int ni = 0; ni < 4; ni++) {
        size_t col = n0 + wn + ni * 16 + l15;
        float v = acc[mi][ni][r];
        if (OUT_F16)
          ((ushort*)Cv)[row * N + col] = f32_to_h_bits(v);
        else
          ((float*)Cv)[row * N + col] = v;
      }
    }
  }
}

// --------------------------------------------------------------- V transpose
// qkv [8192][3072] f16 -> vtg[bh=64][dh=64][key=2048] f16.
__global__ __launch_bounds__(256) void vtrans(const ushort* __restrict__ qkv,
                                              ushort* __restrict__ vtg) {
  __shared__ ushort T[64 * 66];
  const int tid = threadIdx.x;
  const int kt = blockIdx.x;
  const int bh = blockIdx.y;
  const int b = bh >> 4, h = bh & 15;

  const int r = tid >> 3;
  const int c = (tid & 7) * 8;
  const ushort* src = qkv + (size_t)(b * 2048 + kt * 64) * 3072 + 2048 + h * 64;
  uint4 v0 = *(const uint4*)(src + (size_t)r * 3072 + c);
  uint4 v1 = *(const uint4*)(src + (size_t)(r + 32) * 3072 + c);
  union { uint4 u; ushort s[8]; } a0, a1;
  a0.u = v0; a1.u = v1;
#pragma unroll
  for (int j = 0; j < 8; j++) {
    T[(c + j) * 66 + r] = a0.s[j];
    T[(c + j) * 66 + r + 32] = a1.s[j];
  }
  __syncthreads();

  const int d = tid >> 3;
  const int kc = (tid & 7) * 8;
  ushort* dst = vtg + (size_t)bh * 64 * 2048 + (size_t)kt * 64;
  union { uint u[4]; uint4 u4; } o0, o1;
#pragma unroll
  for (int i = 0; i < 4; i++) {
    o0.u[i] = *(const uint*)&T[d * 66 + kc + 2 * i];
    o1.u[i] = *(const uint*)&T[(d + 32) * 66 + kc + 2 * i];
  }
  *(uint4*)(dst + (size_t)d * 2048 + kc) = o0.u4;
  *(uint4*)(dst + (size_t)(d + 32) * 2048 + kc) = o1.u4;
}

// ------------------------------------------------------------ flash attention
// Block = 256 q-rows x (b,h); 4 waves x 64 q (interleaved 16-row granules:
// wave w, sub qs -> q0 = qt*256 + (qs*4+w)*16, so all waves run 4(qt+1) tiles).
// K/V staged via gld16 into chunked [64][32] lane-linear LDS (conflict-free).
// St = K*Q^T (swap); softmax reduces in-lane + shfl_xor 16/32; P round-trips
// LDS rows [q][key] stride 66; O^T = V^T*P; epilogue transposes via LDS.
__global__ __launch_bounds__(256, 2) void attn_fused(const ushort* __restrict__ qkv,
                                                     const ushort* __restrict__ vtg,
                                                     ushort* __restrict__ attn_out) {
  __shared__ ushort KsC[2 * 64 * 32];   // [kc][key][dh_chunk32]
  __shared__ ushort VsC[2 * 64 * 32];   // [kc][dh][key_chunk32]
  __shared__ ushort Ps[4][16 * 66];     // per-wave P (and epilogue O) area

  const int tid = threadIdx.x;
  const int lane = tid & 63;
  const int w = tid >> 6;
  const int l15 = lane & 15;
  const int quad = lane >> 4;
  const int qt = (int)gridDim.x - 1 - (int)blockIdx.x;  // big tiles first
  const int bh = blockIdx.y;
  const int b = bh >> 4;
  const int h = bh & 15;
  const int bS = b * 2048;

  // Q B-frags (B[k=dh][n=q] == Q[q][dh]), pre-scaled by 1/sqrt(64)
  U4H8 qf[4][2];
  int q0s[4];
#pragma unroll
  for (int qs = 0; qs < 4; qs++) {
    q0s[qs] = qt * 256 + (qs * 4 + w) * 16;
    const ushort* qrow = qkv + (size_t)(bS + q0s[qs] + l15) * 3072 + h * 64;
#pragma unroll
    for (int kc = 0; kc < 2; kc++) {
      qf[qs][kc].u = *(const uint4*)(qrow + kc * 32 + quad * 8);
      qf[qs][kc].h = qf[qs][kc].h * (_Float16)0.125f;
    }
  }

  floatx4 o[4][4];  // [qs][dh-tile]; D rows dh=ni*16+quad*4+r, col q=l15
#pragma unroll
  for (int qs = 0; qs < 4; qs++)
#pragma unroll
    for (int ni = 0; ni < 4; ni++) o[qs][ni] = (floatx4){0.f, 0.f, 0.f, 0.f};
  float m_i[4], l_i[4];  // per-lane: stats for q-col l15 (replicated across quads)
#pragma unroll
  for (int qs = 0; qs < 4; qs++) { m_i[qs] = -1e30f; l_i[qs] = 0.f; }

  const int srow = lane >> 2;        // staging row within 16-row group
  const int scc = (lane & 3) * 8;    // staging 8-col chunk
  const ushort* kbase = qkv + (size_t)bS * 3072 + 1024 + h * 64;
  const ushort* vbase = vtg + (size_t)bh * 64 * 2048;
  ushort* KsW0 = &KsC[w * 512];
  ushort* KsW1 = &KsC[2048 + w * 512];
  ushort* VsW0 = &VsC[w * 512];
  ushort* VsW1 = &VsC[2048 + w * 512];

  const int ntiles = 4 * (qt + 1);

  for (int kt = 0; kt < ntiles; ++kt) {
    const int kt64 = kt << 6;
    const bool dz = (kt >= 4 * qt);  // diagonal zone: last 4 tiles
    __syncthreads();  // prior tile consumed
    {
      const ushort* kg = kbase + (size_t)(kt64 + w * 16 + srow) * 3072 + scc;
      const ushort* vg = vbase + (size_t)(w * 16 + srow) * 2048 + kt64 + scc;
      gld16(kg, KsW0);
      gld16(kg + 32, KsW1);
      gld16(vg, VsW0);
      gld16(vg + 32, VsW1);
    }
    __syncthreads();  // barrier drains vmcnt: staged data visible

    // K A-frags (A[m=key][k=dh]) and V^T A-frags (A[m=dh][k=key])
    U4H8 kf[4][2], vf[4][2];
#pragma unroll
    for (int t = 0; t < 4; t++)
#pragma unroll
      for (int kc = 0; kc < 2; kc++)
        kf[t][kc].u = *(const uint4*)&KsC[kc * 2048 + (t * 16 + l15) * 32 + quad * 8];
#pragma unroll
    for (int ni = 0; ni < 4; ni++)
#pragma unroll
      for (int kc = 0; kc < 2; kc++)
        vf[ni][kc].u = *(const uint4*)&VsC[kc * 2048 + (ni * 16 + l15) * 32 + quad * 8];

#pragma unroll
    for (int qs = 0; qs < 4; qs++) {
      const int q0l = q0s[qs];
      const int avail = q0l + 15 - kt64;
      if (dz && avail < 0) continue;  // wave-uniform
      const int n16 = dz ? min(4, (avail >> 4) + 1) : 4;

      floatx4 s4[4];
#pragma unroll
      for (int t = 0; t < 4; t++) s4[t] = (floatx4){-1e30f, -1e30f, -1e30f, -1e30f};
      for (int t = 0; t < n16; t++) {
        floatx4 sa = (floatx4){0.f, 0.f, 0.f, 0.f};
        sa = __builtin_amdgcn_mfma_f32_16x16x32_f16(kf[t][0].h, qf[qs][0].h, sa, 0, 0, 0);
        sa = __builtin_amdgcn_mfma_f32_16x16x32_f16(kf[t][1].h, qf[qs][1].h, sa, 0, 0, 0);
        s4[t] = sa;
      }
      if (dz) {  // mask key > q (St rows are keys, col q = l15)
        const int q = q0l + l15;
#pragma unroll
        for (int t = 0; t < 4; t++)
#pragma unroll
          for (int r = 0; r < 4; r++) {
            int key = kt64 + t * 16 + quad * 4 + r;
            if (key > q) s4[t][r] = -1e30f;
          }
      }

      // ---- online softmax for q-col l15
      float tmax = -1e30f;
#pragma unroll
      for (int t = 0; t < 4; t++)
#pragma unroll
        for (int r = 0; r < 4; r++) tmax = fmaxf(tmax, s4[t][r]);
      tmax = fmaxf(tmax, __shfl_xor(tmax, 16));
      tmax = fmaxf(tmax, __shfl_xor(tmax, 32));
      float mnew = fmaxf(m_i[qs], tmax);
      float alpha = __expf(m_i[qs] - mnew);
      m_i[qs] = mnew;
      float rs = 0.f;
#pragma unroll
      for (int t = 0; t < 4; t++)
#pragma unroll
        for (int r = 0; r < 4; r++) {
          float p = __expf(s4[t][r] - mnew);
          s4[t][r] = p;
          rs += p;
        }
      rs += __shfl_xor(rs, 16);
      rs += __shfl_xor(rs, 32);
      l_i[qs] = l_i[qs] * alpha + rs;
#pragma unroll
      for (int ni = 0; ni < 4; ni++) o[qs][ni] *= alpha;

      // ---- P -> LDS rows [q=l15][key], packed b32 (keys quad*4+{0,1},{2,3})
#pragma unroll
      for (int t = 0; t < 4; t++) {
        *(uint*)&Ps[w][l15 * 66 + t * 16 + quad * 4] = pack2h(s4[t][0], s4[t][1]);
        *(uint*)&Ps[w][l15 * 66 + t * 16 + quad * 4 + 2] = pack2h(s4[t][2], s4[t][3]);
      }
      __asm__ volatile("s_waitcnt lgkmcnt(0)" ::: "memory");  // wave-private RAW

      // ---- O^T += V^T * P  (B-frag: B[k=key][n=q] = Ps[l15][kc*32+quad*8+j])
      U4H8 pb[2];
      pb[0].u = *(const uint4*)&Ps[w][l15 * 66 + quad * 8];
      pb[1].u = *(const uint4*)&Ps[w][l15 * 66 + 32 + quad * 8];
#pragma unroll
      for (int ni = 0; ni < 4; ni++) {
        o[qs][ni] = __builtin_amdgcn_mfma_f32_16x16x32_f16(vf[ni][0].h, pb[0].h,
                                                           o[qs][ni], 0, 0, 0);
        o[qs][ni] = __builtin_amdgcn_mfma_f32_16x16x32_f16(vf[ni][1].h, pb[1].h,
                                                           o[qs][ni], 0, 0, 0);
      }
    }
  }

  // ---- epilogue: O^T (dh=ni*16+quad*4+r, q=l15) -> LDS transpose -> coalesced
#pragma unroll
  for (int qs = 0; qs < 4; qs++) {
    float inv = 1.0f / l_i[qs];
#pragma unroll
    for (int ni = 0; ni < 4; ni++) {
      *(uint*)&Ps[w][l15 * 66 + ni * 16 + quad * 4] =
          pack2h(o[qs][ni][0] * inv, o[qs][ni][1] * inv);
      *(uint*)&Ps[w][l15 * 66 + ni * 16 + quad * 4 + 2] =
          pack2h(o[qs][ni][2] * inv, o[qs][ni][3] * inv);
    }
    __asm__ volatile("s_waitcnt lgkmcnt(0)" ::: "memory");
    ushort* orow = attn_out + (size_t)(bS + q0s[qs] + l15) * 1024 + h * 64;
    uint4 x0 = *(const uint4*)&Ps[w][l15 * 66 + quad * 8];
    uint4 x1 = *(const uint4*)&Ps[w][l15 * 66 + 32 + quad * 8];
    *(uint4*)(orow + quad * 8) = x0;
    *(uint4*)(orow + 32 + quad * 8) = x1;
    __asm__ volatile("s_waitcnt lgkmcnt(0)" ::: "memory");  // reads done before reuse
  }
}

// ---------------------------------------------------------------------- launch
extern "C" void kernel_launch(void* const* d_in, const int* in_sizes, int n_in,
                              void* d_out, int out_size, void* d_ws, size_t ws_size,
                              hipStream_t stream) {
  const float* x = (const float*)d_in[0];       // [4,2048,1024]
  const float* wqkv = (const float*)d_in[1];    // [3072,1024]
  const float* wo = (const float*)d_in[2];      // [1024,1024]
  float* out = (float*)d_out;                   // [4,2048,1024] fp32

  ushort* xh = (ushort*)d_ws;                          // 8192*1024
  ushort* wqkvh = xh + (size_t)8192 * 1024;            // 3072*1024
  ushort* woh = wqkvh + (size_t)3072 * 1024;           // 1024*1024
  ushort* qkvh = woh + (size_t)1024 * 1024;            // 8192*3072
  ushort* attnh = qkvh + (size_t)8192 * 3072;          // 8192*1024
  ushort* vtg = attnh + (size_t)8192 * 1024;           // 64*64*2048
  // total ws use: ~109 MB

  cast_f32_f16<<<8192, 256, 0, stream>>>(x, xh);
  cast_f32_f16<<<3072, 256, 0, stream>>>(wqkv, wqkvh);
  cast_f32_f16<<<1024, 256, 0, stream>>>(wo, woh);

  gemm_bt<1><<<dim3(24, 64), 256, 0, stream>>>(xh, wqkvh, qkvh, 8192, 3072, 1024);
  vtrans<<<dim3(32, 64), 256, 0, stream>>>(qkvh, vtg);
  attn_fused<<<dim3(8, 64), 256, 0, stream>>>(qkvh, vtg, attnh);
  gemm_bt<0><<<dim3(8, 64), 256, 0, stream>>>(attnh, woh, out, 8192, 1024, 1024);
}

// Round 4
// 290.641 us; speedup vs baseline: 1.8665x; 1.8665x over previous
//
#include <hip/hip_runtime.h>

// ---------------------------------------------------------------------------
// Fused causal attention, MI355X gfx950.
// cast fp32->f16 -> QKV GEMM -> V transpose -> flash attention (strip-paired
// uniform blocks, dbuf gld16 K/V, operand-swap, no spills) -> out GEMM.
// MFMA 16x16x32 layouts (m89/m91/m120-verified):
//   A-frag: A[m=lane&15][k=(lane>>4)*8+j], j=0..7
//   B-frag: B[k=(lane>>4)*8+j][n=lane&15]
//   C/D   : row=(lane>>4)*4+reg, col=lane&15
// Attention swap: St = K*Q^T (C: row=key,col=q), O^T = V^T*P.
// ---------------------------------------------------------------------------

typedef _Float16 f16x8 __attribute__((ext_vector_type(8)));
typedef float floatx4 __attribute__((ext_vector_type(4)));

union U4H8 { uint4 u; f16x8 h; };

__device__ __forceinline__ ushort f32_to_h_bits(float f) {
  _Float16 h = (_Float16)f;
  return __builtin_bit_cast(ushort, h);
}
__device__ __forceinline__ uint pack2h(float a, float b) {
  return (uint)f32_to_h_bits(a) | ((uint)f32_to_h_bits(b) << 16);
}

// async global->LDS, 16B/lane; LDS dest = wave-uniform base + lane*16
__device__ __forceinline__ void gld16(const void* g, void* l) {
  __builtin_amdgcn_global_load_lds(
      (const __attribute__((address_space(1))) unsigned char*)g,
      (__attribute__((address_space(3))) unsigned char*)l, 16, 0, 0);
}

// ---------------------------------------------------------------- cast kernel
__global__ __launch_bounds__(256) void cast_f32_f16(const float* __restrict__ in,
                                                    ushort* __restrict__ out) {
  int i = blockIdx.x * 256 + threadIdx.x;
  float4 v = ((const float4*)in)[i];
  ushort4 o;
  o.x = f32_to_h_bits(v.x);
  o.y = f32_to_h_bits(v.y);
  o.z = f32_to_h_bits(v.z);
  o.w = f32_to_h_bits(v.w);
  ((ushort4*)out)[i] = o;
}

// ------------------------------------------------------------------ GEMM B^T
// C[M,N] = A[M,K] * B[N,K]^T.  128x128 tile, BK=32, 4 waves 2x2, 4x4 MFMA.
template <int OUT_F16>
__global__ __launch_bounds__(256) void gemm_bt(const ushort* __restrict__ A,
                                               const ushort* __restrict__ B,
                                               void* __restrict__ Cv,
                                               int M, int N, int K) {
  __shared__ ushort As[128 * 32];
  __shared__ ushort Bs[128 * 32];

  const int tid = threadIdx.x;
  const int lane = tid & 63;
  const int wid = tid >> 6;
  const int l15 = lane & 15;
  const int quad = lane >> 4;
  const int m0 = blockIdx.y * 128;
  const int n0 = blockIdx.x * 128;
  const int wm = (wid & 1) * 64;
  const int wn = (wid >> 1) * 64;

  floatx4 acc[4][4];
#pragma unroll
  for (int i = 0; i < 4; i++)
#pragma unroll
    for (int j = 0; j < 4; j++) acc[i][j] = (floatx4){0.f, 0.f, 0.f, 0.f};

  const int srow = tid >> 2;
  const int scol = (tid & 3) * 8;
  const ushort* Ap0 = A + (size_t)(m0 + srow) * K + scol;
  const ushort* Ap1 = A + (size_t)(m0 + 64 + srow) * K + scol;
  const ushort* Bp0 = B + (size_t)(n0 + srow) * K + scol;
  const ushort* Bp1 = B + (size_t)(n0 + 64 + srow) * K + scol;
  ushort* AsW = As + wid * 512;
  ushort* BsW = Bs + wid * 512;

  for (int k0 = 0; k0 < K; k0 += 32) {
    __syncthreads();
    gld16(Ap0 + k0, AsW);
    gld16(Ap1 + k0, AsW + 2048);
    gld16(Bp0 + k0, BsW);
    gld16(Bp1 + k0, BsW + 2048);
    __syncthreads();

    U4H8 af[4], bf[4];
#pragma unroll
    for (int mi = 0; mi < 4; mi++)
      af[mi].u = *(const uint4*)&As[(wm + mi * 16 + l15) * 32 + quad * 8];
#pragma unroll
    for (int ni = 0; ni < 4; ni++)
      bf[ni].u = *(const uint4*)&Bs[(wn + ni * 16 + l15) * 32 + quad * 8];
#pragma unroll
    for (int mi = 0; mi < 4; mi++)
#pragma unroll
      for (int ni = 0; ni < 4; ni++)
        acc[mi][ni] = __builtin_amdgcn_mfma_f32_16x16x32_f16(af[mi].h, bf[ni].h,
                                                             acc[mi][ni], 0, 0, 0);
  }

#pragma unroll
  for (int mi = 0; mi < 4; mi++) {
#pragma unroll
    for (int r = 0; r < 4; r++) {
      size_t row = m0 + wm + mi * 16 + quad * 4 + r;
#pragma unroll
      for (int ni = 0; ni < 4; ni++) {
        size_t col = n0 + wn + ni * 16 + l15;
        float v = acc[mi][ni][r];
        if (OUT_F16)
          ((ushort*)Cv)[row * N + col] = f32_to_h_bits(v);
        else
          ((float*)Cv)[row * N + col] = v;
      }
    }
  }
}

// --------------------------------------------------------------- V transpose
// qkv [8192][3072] f16 -> vtg[bh=64][dh=64][key=2048] f16.
__global__ __launch_bounds__(256) void vtrans(const ushort* __restrict__ qkv,
                                              ushort* __restrict__ vtg) {
  __shared__ ushort T[64 * 66];
  const int tid = threadIdx.x;
  const int kt = blockIdx.x;
  const int bh = blockIdx.y;
  const int b = bh >> 4, h = bh & 15;

  const int r = tid >> 3;
  const int c = (tid & 7) * 8;
  const ushort* src = qkv + (size_t)(b * 2048 + kt * 64) * 3072 + 2048 + h * 64;
  uint4 v0 = *(const uint4*)(src + (size_t)r * 3072 + c);
  uint4 v1 = *(const uint4*)(src + (size_t)(r + 32) * 3072 + c);
  union { uint4 u; ushort s[8]; } a0, a1;
  a0.u = v0; a1.u = v1;
#pragma unroll
  for (int j = 0; j < 8; j++) {
    T[(c + j) * 66 + r] = a0.s[j];
    T[(c + j) * 66 + r + 32] = a1.s[j];
  }
  __syncthreads();

  const int d = tid >> 3;
  const int kc = (tid & 7) * 8;
  ushort* dst = vtg + (size_t)bh * 64 * 2048 + (size_t)kt * 64;
  union { uint u[4]; uint4 u4; } o0, o1;
#pragma unroll
  for (int i = 0; i < 4; i++) {
    o0.u[i] = *(const uint*)&T[d * 66 + kc + 2 * i];
    o1.u[i] = *(const uint*)&T[(d + 32) * 66 + kc + 2 * i];
  }
  *(uint4*)(dst + (size_t)d * 2048 + kc) = o0.u4;
  *(uint4*)(dst + (size_t)(d + 32) * 2048 + kc) = o1.u4;
}

// ------------------------------------------------------------ flash attention
// Block = strip pair (bx, 31-bx), each strip 64 q; wave w owns q granules
// qA = bx*64+w*16 and qB = (31-bx)*64+w*16 -> exactly 33 strip-tile units per
// block (uniform). 1024 blocks, 4/CU all-resident, 16 waves/CU.
// K/V double-buffered via gld16 (prefetch kt+1 after the barrier).
__global__ __launch_bounds__(256, 4) void attn_fused(const ushort* __restrict__ qkv,
                                                     const ushort* __restrict__ vtg,
                                                     ushort* __restrict__ attn_out) {
  __shared__ ushort Ks[2][2][64 * 32];  // [buf][kc_dh][key][dh32]   16 KB
  __shared__ ushort Vs[2][2][64 * 32];  // [buf][kc_key][dh][key32]  16 KB
  __shared__ ushort Ps[4][16 * 40];     // per-wave P half-tile       5 KB

  const int tid = threadIdx.x;
  const int lane = tid & 63;
  const int w = tid >> 6;
  const int l15 = lane & 15;
  const int quad = lane >> 4;
  const int bx = blockIdx.x;            // 0..15
  const int bh = blockIdx.y;
  const int b = bh >> 4;
  const int h = bh & 15;
  const int bS = b * 2048;
  const int qtA = bx;
  const int qtB = 31 - bx;
  const int ktmax = qtB;
  int q0s[2];
  q0s[0] = qtA * 64 + w * 16;
  q0s[1] = qtB * 64 + w * 16;

  // Q B-frags (B[k=dh][n=q] == Q[q][dh]), pre-scaled by 1/sqrt(64)
  U4H8 qf[2][2];
#pragma unroll
  for (int s = 0; s < 2; s++) {
    const ushort* qrow = qkv + (size_t)(bS + q0s[s] + l15) * 3072 + h * 64;
#pragma unroll
    for (int kc = 0; kc < 2; kc++) {
      qf[s][kc].u = *(const uint4*)(qrow + kc * 32 + quad * 8);
      qf[s][kc].h = qf[s][kc].h * (_Float16)0.125f;
    }
  }

  floatx4 o[2][4];  // [strip][dh tile]; D: dh=ni*16+quad*4+r, q=l15
#pragma unroll
  for (int s = 0; s < 2; s++)
#pragma unroll
    for (int ni = 0; ni < 4; ni++) o[s][ni] = (floatx4){0.f, 0.f, 0.f, 0.f};
  float m_i[2] = {-1e30f, -1e30f}, l_i[2] = {0.f, 0.f};

  const ushort* kbase = qkv + (size_t)bS * 3072 + 1024 + h * 64;
  const ushort* vbase = vtg + (size_t)bh * 64 * 2048;
  const int srow = lane >> 2;        // 16 rows per wave per gld16
  const int scc = (lane & 3) * 8;    // 8-ushort chunk

  auto stage = [&](int kt, int buf) {
    const ushort* kg = kbase + (size_t)(kt * 64 + w * 16 + srow) * 3072 + scc;
    gld16(kg, &Ks[buf][0][w * 512]);
    gld16(kg + 32, &Ks[buf][1][w * 512]);
    const ushort* vg = vbase + (size_t)(w * 16 + srow) * 2048 + kt * 64 + scc;
    gld16(vg, &Vs[buf][0][w * 512]);
    gld16(vg + 32, &Vs[buf][1][w * 512]);
  };

  auto strip_step = [&](int s, bool diag, int kt64, int buf) {
    // ---- St = K Q^T  (all 4 subtiles; diagonal handled by mask)
    floatx4 s4[4];
#pragma unroll
    for (int t = 0; t < 4; t++) {
      U4H8 kf0, kf1;
      kf0.u = *(const uint4*)&Ks[buf][0][(t * 16 + l15) * 32 + quad * 8];
      kf1.u = *(const uint4*)&Ks[buf][1][(t * 16 + l15) * 32 + quad * 8];
      floatx4 sa = (floatx4){0.f, 0.f, 0.f, 0.f};
      sa = __builtin_amdgcn_mfma_f32_16x16x32_f16(kf0.h, qf[s][0].h, sa, 0, 0, 0);
      sa = __builtin_amdgcn_mfma_f32_16x16x32_f16(kf1.h, qf[s][1].h, sa, 0, 0, 0);
      s4[t] = sa;
    }
    if (diag) {
      const int q = q0s[s] + l15;
#pragma unroll
      for (int t = 0; t < 4; t++)
#pragma unroll
        for (int r = 0; r < 4; r++) {
          int key = kt64 + t * 16 + quad * 4 + r;
          if (key > q) s4[t][r] = -1e30f;
        }
    }

    // ---- online softmax (16 in-lane keys + quads via shfl 16/32)
    float tmax = -1e30f;
#pragma unroll
    for (int t = 0; t < 4; t++)
#pragma unroll
      for (int r = 0; r < 4; r++) tmax = fmaxf(tmax, s4[t][r]);
    tmax = fmaxf(tmax, __shfl_xor(tmax, 16));
    tmax = fmaxf(tmax, __shfl_xor(tmax, 32));
    float mnew = fmaxf(m_i[s], tmax);
    float alpha = __expf(m_i[s] - mnew);
    m_i[s] = mnew;
    float rs = 0.f;
#pragma unroll
    for (int t = 0; t < 4; t++)
#pragma unroll
      for (int r = 0; r < 4; r++) {
        float p = __expf(s4[t][r] - mnew);
        s4[t][r] = p;
        rs += p;
      }
    rs += __shfl_xor(rs, 16);
    rs += __shfl_xor(rs, 32);
    l_i[s] = l_i[s] * alpha + rs;
#pragma unroll
    for (int ni = 0; ni < 4; ni++) o[s][ni] *= alpha;

    // ---- O^T += V^T P, split by 32-key halves (Ps rows are 32 wide)
#pragma unroll
    for (int kc = 0; kc < 2; kc++) {
#pragma unroll
      for (int th = 0; th < 2; th++) {
        const int t = kc * 2 + th;
        *(uint*)&Ps[w][l15 * 40 + th * 16 + quad * 4] = pack2h(s4[t][0], s4[t][1]);
        *(uint*)&Ps[w][l15 * 40 + th * 16 + quad * 4 + 2] = pack2h(s4[t][2], s4[t][3]);
      }
      __asm__ volatile("s_waitcnt lgkmcnt(0)" ::: "memory");  // wave-private RAW
      U4H8 pb;
      pb.u = *(const uint4*)&Ps[w][l15 * 40 + quad * 8];
#pragma unroll
      for (int ni = 0; ni < 4; ni++) {
        U4H8 vf;
        vf.u = *(const uint4*)&Vs[buf][kc][(ni * 16 + l15) * 32 + quad * 8];
        o[s][ni] = __builtin_amdgcn_mfma_f32_16x16x32_f16(vf.h, pb.h, o[s][ni], 0, 0, 0);
      }
    }
  };

  stage(0, 0);
  for (int kt = 0; kt <= ktmax; ++kt) {
    const int buf = kt & 1;
    __syncthreads();  // drains vmcnt -> buf staged; prior LDS reads done
    if (kt < ktmax) stage(kt + 1, buf ^ 1);
    strip_step(1, kt == qtB, kt * 64, buf);
    if (kt <= qtA) strip_step(0, kt == qtA, kt * 64, buf);
  }

  // ---- epilogue: O^T -> transpose via Ps (two 32-col passes) -> coalesced
#pragma unroll
  for (int s = 0; s < 2; s++) {
    float inv = 1.0f / l_i[s];
    ushort* orow = attn_out + (size_t)(bS + q0s[s] + l15) * 1024 + h * 64;
#pragma unroll
    for (int p = 0; p < 2; p++) {
#pragma unroll
      for (int nh = 0; nh < 2; nh++) {
        const int ni = p * 2 + nh;
        *(uint*)&Ps[w][l15 * 40 + nh * 16 + quad * 4] =
            pack2h(o[s][ni][0] * inv, o[s][ni][1] * inv);
        *(uint*)&Ps[w][l15 * 40 + nh * 16 + quad * 4 + 2] =
            pack2h(o[s][ni][2] * inv, o[s][ni][3] * inv);
      }
      __asm__ volatile("s_waitcnt lgkmcnt(0)" ::: "memory");
      uint4 x = *(const uint4*)&Ps[w][l15 * 40 + quad * 8];
      *(uint4*)(orow + p * 32 + quad * 8) = x;
      __asm__ volatile("s_waitcnt lgkmcnt(0)" ::: "memory");  // reads before reuse
    }
  }
}

// ---------------------------------------------------------------------- launch
extern "C" void kernel_launch(void* const* d_in, const int* in_sizes, int n_in,
                              void* d_out, int out_size, void* d_ws, size_t ws_size,
                              hipStream_t stream) {
  const float* x = (const float*)d_in[0];       // [4,2048,1024]
  const float* wqkv = (const float*)d_in[1];    // [3072,1024]
  const float* wo = (const float*)d_in[2];      // [1024,1024]
  float* out = (float*)d_out;                   // [4,2048,1024] fp32

  ushort* xh = (ushort*)d_ws;                          // 8192*1024
  ushort* wqkvh = xh + (size_t)8192 * 1024;            // 3072*1024
  ushort* woh = wqkvh + (size_t)3072 * 1024;           // 1024*1024
  ushort* qkvh = woh + (size_t)1024 * 1024;            // 8192*3072
  ushort* attnh = qkvh + (size_t)8192 * 3072;          // 8192*1024
  ushort* vtg = attnh + (size_t)8192 * 1024;           // 64*64*2048
  // total ws use: ~109 MB

  cast_f32_f16<<<8192, 256, 0, stream>>>(x, xh);
  cast_f32_f16<<<3072, 256, 0, stream>>>(wqkv, wqkvh);
  cast_f32_f16<<<1024, 256, 0, stream>>>(wo, woh);

  gemm_bt<1><<<dim3(24, 64), 256, 0, stream>>>(xh, wqkvh, qkvh, 8192, 3072, 1024);
  vtrans<<<dim3(32, 64), 256, 0, stream>>>(qkvh, vtg);
  attn_fused<<<dim3(16, 64), 256, 0, stream>>>(qkvh, vtg, attnh);
  gemm_bt<0><<<dim3(8, 64), 256, 0, stream>>>(attnh, woh, out, 8192, 1024, 1024);
}